// Round 1
// baseline (2499.322 us; speedup 1.0000x reference)
//
#include <hip/hip_runtime.h>
#include <hip/hip_bf16.h>

#define T_SEQ 2048
#define CDIM  1024
#define NH    16
#define HD    64
#define BATCH 4
#define MROWS (BATCH * T_SEQ)   // 8192

// ---------------------------------------------------------------------------
// 128x128 fp32 tiled GEMM, 256 threads, 8x8 accumulators per thread (4+4 split
// so LDS float4 reads are 16B-lane-stride = conflict-free).
// C = A[M,K] @ W[K,N], both row-major.
// SCATTER=0: plain store into C0[M,N].
// SCATTER=1: N == 3*CDIM; columns scattered into q/k/v with [B,H,T,hd] layout.
// ---------------------------------------------------------------------------
template<int SCATTER>
__global__ __launch_bounds__(256)
void gemm128(const float* __restrict__ A, const float* __restrict__ W,
             float* __restrict__ C0, float* __restrict__ C1,
             float* __restrict__ C2, int M, int N, int K)
{
    __shared__ float As[8][128];   // [k][m]
    __shared__ float Bs[8][128];   // [k][n]

    const int tid = threadIdx.x;
    const int tx  = tid & 15;      // n-quad
    const int ty  = tid >> 4;      // m-quad
    const int m0  = blockIdx.x * 128;
    const int n0  = blockIdx.y * 128;

    // A-tile: 128 rows x 8 k = 256 float4 (one per thread)
    const int a_k4 = (tid & 1) * 4;
    const int a_m  = tid >> 1;
    // B-tile: 8 k x 128 n = 256 float4 (one per thread)
    const int b_n4 = (tid & 31) * 4;
    const int b_kk = tid >> 5;

    float acc[8][8];
    #pragma unroll
    for (int i = 0; i < 8; ++i)
        #pragma unroll
        for (int j = 0; j < 8; ++j) acc[i][j] = 0.0f;

    for (int k0 = 0; k0 < K; k0 += 8) {
        float4 av = *(const float4*)&A[(size_t)(m0 + a_m) * K + (k0 + a_k4)];
        float4 bv = *(const float4*)&W[(size_t)(k0 + b_kk) * N + (n0 + b_n4)];
        __syncthreads();           // previous iteration's LDS reads done
        As[a_k4 + 0][a_m] = av.x;
        As[a_k4 + 1][a_m] = av.y;
        As[a_k4 + 2][a_m] = av.z;
        As[a_k4 + 3][a_m] = av.w;
        *(float4*)&Bs[b_kk][b_n4] = bv;
        __syncthreads();           // tile ready
        #pragma unroll
        for (int kk = 0; kk < 8; ++kk) {
            float a[8], b[8];
            *(float4*)&a[0] = *(const float4*)&As[kk][ty * 4];
            *(float4*)&a[4] = *(const float4*)&As[kk][64 + ty * 4];
            *(float4*)&b[0] = *(const float4*)&Bs[kk][tx * 4];
            *(float4*)&b[4] = *(const float4*)&Bs[kk][64 + tx * 4];
            #pragma unroll
            for (int i = 0; i < 8; ++i)
                #pragma unroll
                for (int j = 0; j < 8; ++j)
                    acc[i][j] = fmaf(a[i], b[j], acc[i][j]);
        }
    }

    if (SCATTER == 0) {
        #pragma unroll
        for (int ri = 0; ri < 2; ++ri)
            #pragma unroll
            for (int i = 0; i < 4; ++i) {
                const int m = m0 + ri * 64 + ty * 4 + i;
                #pragma unroll
                for (int rj = 0; rj < 2; ++rj) {
                    float4 vv;
                    vv.x = acc[ri*4+i][rj*4+0];
                    vv.y = acc[ri*4+i][rj*4+1];
                    vv.z = acc[ri*4+i][rj*4+2];
                    vv.w = acc[ri*4+i][rj*4+3];
                    *(float4*)&C0[(size_t)m * N + (n0 + rj * 64 + tx * 4)] = vv;
                }
            }
    } else {
        // column block n0..n0+127 lies entirely inside one of q/k/v
        const int which = n0 >> 10;
        float* dst = (which == 0) ? C0 : ((which == 1) ? C1 : C2);
        const int h0 = (n0 & (CDIM - 1)) >> 6;   // base head of this 128-col tile
        const int b  = m0 >> 11;                 // row block entirely inside one batch
        const int t0 = m0 & (T_SEQ - 1);
        #pragma unroll
        for (int ri = 0; ri < 2; ++ri)
            #pragma unroll
            for (int i = 0; i < 4; ++i) {
                const int t = t0 + ri * 64 + ty * 4 + i;
                #pragma unroll
                for (int rj = 0; rj < 2; ++rj) {
                    const int h = h0 + rj;       // rj*64 jumps exactly one head
                    float4 vv;
                    vv.x = acc[ri*4+i][rj*4+0];
                    vv.y = acc[ri*4+i][rj*4+1];
                    vv.z = acc[ri*4+i][rj*4+2];
                    vv.w = acc[ri*4+i][rj*4+3];
                    *(float4*)&dst[((size_t)(b * NH + h) * T_SEQ + t) * HD + (tx * 4)] = vv;
                }
            }
    }
}

// ---------------------------------------------------------------------------
// Flash attention fp32, causal + relative-position bias.
// One block per (b, h, 64-row q-tile); 256 threads; online softmax.
// q/k/v layout [B,H,T,hd]; y written as [B,T,H*hd].
// ---------------------------------------------------------------------------
__global__ __launch_bounds__(256)
void attn_kernel(const float* __restrict__ q, const float* __restrict__ k,
                 const float* __restrict__ v, const float* __restrict__ rb,
                 float* __restrict__ y)
{
    const int bh = blockIdx.y;           // b*NH + h
    const int h  = bh & (NH - 1);
    const int b  = bh >> 4;
    const int q0 = blockIdx.x * 64;

    const float* Q  = q + (size_t)bh * T_SEQ * HD;
    const float* Kp = k + (size_t)bh * T_SEQ * HD;
    const float* Vp = v + (size_t)bh * T_SEQ * HD;

    __shared__ float Qs[64][HD + 1];
    __shared__ float Ks[64][HD + 1];
    __shared__ float Vs[64][HD + 1];
    __shared__ float Ps[64][64 + 1];

    const int tid = threadIdx.x;
    const int tx  = tid & 15;            // col quad (j or d)
    const int ty  = tid >> 4;            // row quad (i)

    for (int idx = tid; idx < 64 * HD; idx += 256) {
        const int r = idx >> 6, d = idx & 63;
        Qs[r][d] = Q[(size_t)(q0 + r) * HD + d];
    }

    float mcur[4], lcur[4], O[4][4];
    #pragma unroll
    for (int i = 0; i < 4; ++i) {
        mcur[i] = -1e30f; lcur[i] = 0.0f;
        #pragma unroll
        for (int j = 0; j < 4; ++j) O[i][j] = 0.0f;
    }

    const int nkt = blockIdx.x + 1;      // causal: k-tiles 0..qtile
    for (int kt = 0; kt < nkt; ++kt) {
        const int j0 = kt * 64;
        for (int idx = tid; idx < 64 * HD; idx += 256) {
            const int r = idx >> 6, d = idx & 63;
            Ks[r][d] = Kp[(size_t)(j0 + r) * HD + d];
            Vs[r][d] = Vp[(size_t)(j0 + r) * HD + d];
        }
        __syncthreads();                 // K/V tiles ready (and Qs on first iter)

        // S = Q K^T (4x4 per thread)
        float s[4][4];
        #pragma unroll
        for (int i = 0; i < 4; ++i)
            #pragma unroll
            for (int j = 0; j < 4; ++j) s[i][j] = 0.0f;
        for (int d = 0; d < HD; ++d) {
            float a[4], bb[4];
            #pragma unroll
            for (int i = 0; i < 4; ++i) a[i] = Qs[ty * 4 + i][d];
            #pragma unroll
            for (int j = 0; j < 4; ++j) bb[j] = Ks[tx * 4 + j][d];
            #pragma unroll
            for (int i = 0; i < 4; ++i)
                #pragma unroll
                for (int j = 0; j < 4; ++j)
                    s[i][j] = fmaf(a[i], bb[j], s[i][j]);
        }

        // scale + rel-bias + causal mask, then online softmax per row
        #pragma unroll
        for (int i = 0; i < 4; ++i) {
            const int gi = q0 + ty * 4 + i;
            #pragma unroll
            for (int j = 0; j < 4; ++j) {
                const int gj = j0 + tx * 4 + j;
                if (gj > gi) s[i][j] = -1e30f;
                else         s[i][j] = s[i][j] * 0.125f + rb[(size_t)(gi - gj) * NH + h];
            }
            float rm = fmaxf(fmaxf(s[i][0], s[i][1]), fmaxf(s[i][2], s[i][3]));
            #pragma unroll
            for (int msk = 1; msk < 16; msk <<= 1)
                rm = fmaxf(rm, __shfl_xor(rm, msk));   // 16-lane row group
            const float mnew  = fmaxf(mcur[i], rm);
            const float scale = __expf(mcur[i] - mnew);
            float psum = 0.0f;
            #pragma unroll
            for (int j = 0; j < 4; ++j) {
                const float p = __expf(s[i][j] - mnew);
                s[i][j] = p; psum += p;
            }
            #pragma unroll
            for (int msk = 1; msk < 16; msk <<= 1)
                psum += __shfl_xor(psum, msk);
            lcur[i] = lcur[i] * scale + psum;
            mcur[i] = mnew;
            #pragma unroll
            for (int j = 0; j < 4; ++j) O[i][j] *= scale;
            #pragma unroll
            for (int j = 0; j < 4; ++j) Ps[ty * 4 + i][tx * 4 + j] = s[i][j];
        }
        __syncthreads();                 // Ps ready; all Ks reads done

        // O += P @ V (thread owns rows ty*4.., dims tx*4..)
        for (int jj = 0; jj < 64; ++jj) {
            float a[4], vv[4];
            #pragma unroll
            for (int i = 0; i < 4; ++i) a[i] = Ps[ty * 4 + i][jj];
            #pragma unroll
            for (int j = 0; j < 4; ++j) vv[j] = Vs[jj][tx * 4 + j];
            #pragma unroll
            for (int i = 0; i < 4; ++i)
                #pragma unroll
                for (int j = 0; j < 4; ++j)
                    O[i][j] = fmaf(a[i], vv[j], O[i][j]);
        }
        __syncthreads();                 // Vs/Ps reads done before next overwrite
    }

    // y[b, t, h*64 + d]
    #pragma unroll
    for (int i = 0; i < 4; ++i) {
        const int t = q0 + ty * 4 + i;
        const float inv = 1.0f / lcur[i];
        float4 vv;
        vv.x = O[i][0] * inv; vv.y = O[i][1] * inv;
        vv.z = O[i][2] * inv; vv.w = O[i][3] * inv;
        *(float4*)&y[((size_t)(b * T_SEQ + t)) * CDIM + h * HD + tx * 4] = vv;
    }
}

extern "C" void kernel_launch(void* const* d_in, const int* in_sizes, int n_in,
                              void* d_out, int out_size, void* d_ws, size_t ws_size,
                              hipStream_t stream)
{
    const float* x     = (const float*)d_in[0];   // [B,T,C]
    const float* Wqkv  = (const float*)d_in[1];   // [C,3C]
    const float* Wproj = (const float*)d_in[2];   // [C,C]
    const float* rb    = (const float*)d_in[3];   // [MAX_LEN,NH]
    float* out = (float*)d_out;                   // [B,T,C]

    const size_t per = (size_t)BATCH * NH * T_SEQ * HD;   // 8.39M floats
    float* qb = (float*)d_ws;
    float* kb = qb + per;
    float* vb = kb + per;
    float* yb = vb + per;
    if (ws_size < 4 * per * sizeof(float)) return;        // need 128 MiB scratch

    dim3 g1(MROWS / 128, (3 * CDIM) / 128);               // 64 x 24
    gemm128<1><<<g1, dim3(256), 0, stream>>>(x, Wqkv, qb, kb, vb,
                                             MROWS, 3 * CDIM, CDIM);

    dim3 g2(T_SEQ / 64, BATCH * NH);                      // 32 x 64
    attn_kernel<<<g2, dim3(256), 0, stream>>>(qb, kb, vb, rb, yb);

    dim3 g3(MROWS / 128, CDIM / 128);                     // 64 x 8
    gemm128<0><<<g3, dim3(256), 0, stream>>>(yb, Wproj, out, nullptr, nullptr,
                                             MROWS, CDIM, CDIM);
}

// Round 4
// 1102.693 us; speedup vs baseline: 2.2666x; 2.2666x over previous
//
#include <hip/hip_runtime.h>
#include <hip/hip_bf16.h>

#define T_SEQ 2048
#define CDIM  1024
#define NH    16
#define HD    64
#define BATCH 4
#define MROWS (BATCH * T_SEQ)   // 8192

typedef __attribute__((ext_vector_type(8))) short bf16x8;
typedef __attribute__((ext_vector_type(4))) float f32x4;

__device__ __forceinline__ ushort f2bf(float f) {
    // round-to-nearest-even fp32 -> bf16 (no NaN handling needed here)
    unsigned u = __float_as_uint(f);
    unsigned r = (u + 0x7fffu + ((u >> 16) & 1u)) >> 16;
    return (ushort)r;
}

// ---------------------------------------------------------------------------
// 128x128 fp32 tiled GEMM, 256 threads, 8x8 accumulators per thread.
// C = A[M,K] @ W[K,N], both row-major.
// SCATTER=0: plain fp32 store into C0[M,N].
// SCATTER=1: N == 3*CDIM; columns scattered as bf16 into
//            q[B,H,T,64], k[B,H,T,64], vT[B,H,64,T].
// ---------------------------------------------------------------------------
template<int SCATTER>
__global__ __launch_bounds__(256)
void gemm128(const float* __restrict__ A, const float* __restrict__ W,
             float* __restrict__ C0, ushort* __restrict__ Q0,
             ushort* __restrict__ K0, ushort* __restrict__ V0,
             int M, int N, int K)
{
    __shared__ float As[8][128];   // [k][m]
    __shared__ float Bs[8][128];   // [k][n]

    const int tid = threadIdx.x;
    const int tx  = tid & 15;      // n-quad
    const int ty  = tid >> 4;      // m-quad
    const int m0  = blockIdx.x * 128;
    const int n0  = blockIdx.y * 128;

    const int a_k4 = (tid & 1) * 4;
    const int a_m  = tid >> 1;
    const int b_n4 = (tid & 31) * 4;
    const int b_kk = tid >> 5;

    float acc[8][8];
    #pragma unroll
    for (int i = 0; i < 8; ++i)
        #pragma unroll
        for (int j = 0; j < 8; ++j) acc[i][j] = 0.0f;

    for (int k0 = 0; k0 < K; k0 += 8) {
        float4 av = *(const float4*)&A[(size_t)(m0 + a_m) * K + (k0 + a_k4)];
        float4 bv = *(const float4*)&W[(size_t)(k0 + b_kk) * N + (n0 + b_n4)];
        __syncthreads();
        As[a_k4 + 0][a_m] = av.x;
        As[a_k4 + 1][a_m] = av.y;
        As[a_k4 + 2][a_m] = av.z;
        As[a_k4 + 3][a_m] = av.w;
        *(float4*)&Bs[b_kk][b_n4] = bv;
        __syncthreads();
        #pragma unroll
        for (int kk = 0; kk < 8; ++kk) {
            float a[8], b[8];
            *(float4*)&a[0] = *(const float4*)&As[kk][ty * 4];
            *(float4*)&a[4] = *(const float4*)&As[kk][64 + ty * 4];
            *(float4*)&b[0] = *(const float4*)&Bs[kk][tx * 4];
            *(float4*)&b[4] = *(const float4*)&Bs[kk][64 + tx * 4];
            #pragma unroll
            for (int i = 0; i < 8; ++i)
                #pragma unroll
                for (int j = 0; j < 8; ++j)
                    acc[i][j] = fmaf(a[i], b[j], acc[i][j]);
        }
    }

    if (SCATTER == 0) {
        #pragma unroll
        for (int ri = 0; ri < 2; ++ri)
            #pragma unroll
            for (int i = 0; i < 4; ++i) {
                const int m = m0 + ri * 64 + ty * 4 + i;
                #pragma unroll
                for (int rj = 0; rj < 2; ++rj) {
                    float4 vv;
                    vv.x = acc[ri*4+i][rj*4+0];
                    vv.y = acc[ri*4+i][rj*4+1];
                    vv.z = acc[ri*4+i][rj*4+2];
                    vv.w = acc[ri*4+i][rj*4+3];
                    *(float4*)&C0[(size_t)m * N + (n0 + rj * 64 + tx * 4)] = vv;
                }
            }
    } else {
        const int which = n0 >> 10;              // 0=q 1=k 2=v
        const int nn = n0 & (CDIM - 1);
        const int h0 = nn >> 6;
        const int b  = m0 >> 11;
        const int t0 = m0 & (T_SEQ - 1);
        if (which < 2) {
            ushort* dst = (which == 0) ? Q0 : K0;   // [B,H,T,64] bf16
            #pragma unroll
            for (int ri = 0; ri < 2; ++ri)
                #pragma unroll
                for (int i = 0; i < 4; ++i) {
                    const int t = t0 + ri * 64 + ty * 4 + i;
                    #pragma unroll
                    for (int rj = 0; rj < 2; ++rj) {
                        const int hh = h0 + rj;
                        ushort4 w4;
                        w4.x = f2bf(acc[ri*4+i][rj*4+0]);
                        w4.y = f2bf(acc[ri*4+i][rj*4+1]);
                        w4.z = f2bf(acc[ri*4+i][rj*4+2]);
                        w4.w = f2bf(acc[ri*4+i][rj*4+3]);
                        *(ushort4*)&dst[((size_t)(b * NH + hh) * T_SEQ + t) * HD + tx * 4] = w4;
                    }
                }
        } else {
            // V transposed: [B,H,64,T] bf16, pack 4 consecutive t per store
            #pragma unroll
            for (int rj = 0; rj < 2; ++rj) {
                const int hh = h0 + rj;
                #pragma unroll
                for (int j = 0; j < 4; ++j) {
                    const int d = tx * 4 + j;
                    #pragma unroll
                    for (int ri = 0; ri < 2; ++ri) {
                        const int tt = t0 + ri * 64 + ty * 4;
                        ushort4 w4;
                        w4.x = f2bf(acc[ri*4+0][rj*4+j]);
                        w4.y = f2bf(acc[ri*4+1][rj*4+j]);
                        w4.z = f2bf(acc[ri*4+2][rj*4+j]);
                        w4.w = f2bf(acc[ri*4+3][rj*4+j]);
                        *(ushort4*)&V0[((size_t)(b * NH + hh) * HD + d) * T_SEQ + tt] = w4;
                    }
                }
            }
        }
    }
}

// ---------------------------------------------------------------------------
// Flash attention, bf16 MFMA (16x16x32), causal + relative-position bias.
// Block = 256 threads = 4 waves; wave w owns q-rows [q0+16w, q0+16w+16).
// K tile [64 kcol][64 d] and V^T tile [64 d][64 kcol] staged in LDS as bf16
// with XOR swizzle byte ^= (row&7)<<4 (row stride 128B would be 32-way).
// S/O accumulator D-layout: col = lane&15, row = (lane>>4)*4 + reg.
// ---------------------------------------------------------------------------
__global__ __launch_bounds__(256)
void attn_mfma(const ushort* __restrict__ qb, const ushort* __restrict__ kb,
               const ushort* __restrict__ vb, const float* __restrict__ rb,
               float* __restrict__ y)
{
    __shared__ __align__(16) char KsB[64 * 128];
    __shared__ __align__(16) char VtB[64 * 128];
    __shared__ __align__(16) char PsB[4][16 * 128];
    __shared__ float rbs[T_SEQ];

    const int tid  = threadIdx.x;
    const int wave = tid >> 6;
    const int lane = tid & 63;
    const int lr   = lane & 15;     // frag col (n) / A-row
    const int lg   = lane >> 4;     // frag k-group
    const int bh   = blockIdx.y;
    const int h    = bh & (NH - 1);
    const int b    = bh >> 4;
    const int q0   = blockIdx.x * 64;

    // stage this head's rel-bias column (dist in [0, q0+64))
    for (int i = tid; i < q0 + 64; i += 256) rbs[i] = rb[(size_t)i * NH + h];

    // Q fragments in registers: rows q0+16w+lr, k = 32*ks + 8*lg + j
    const ushort* qrow = qb + ((size_t)bh * T_SEQ + q0 + wave * 16 + lr) * HD;
    const bf16x8 aq0 = *(const bf16x8*)(qrow + lg * 8);
    const bf16x8 aq1 = *(const bf16x8*)(qrow + 32 + lg * 8);

    const f32x4 zero4 = {0.f, 0.f, 0.f, 0.f};
    f32x4 Oa[4] = {zero4, zero4, zero4, zero4};
    float m_r[4], l_r[4];
    #pragma unroll
    for (int r4 = 0; r4 < 4; ++r4) { m_r[r4] = -3e38f; l_r[r4] = 0.f; }

    const ushort* kbp = kb + (size_t)bh * T_SEQ * HD;
    const ushort* vbp = vb + (size_t)bh * HD * T_SEQ;

    const int nkt = blockIdx.x + 1;      // causal
    for (int kt = 0; kt < nkt; ++kt) {
        const int j0 = kt * 64;

        // stage K and V^T tiles (each thread: 2 x 16B for each)
        #pragma unroll
        for (int s = 0; s < 2; ++s) {
            const int cid = tid + s * 256;
            const int r  = cid >> 3;
            const int cb = (cid & 7) * 16;
            const int sw = (r & 7) << 4;
            int4 kv = *(const int4*)((const char*)(kbp + (size_t)(j0 + r) * HD) + cb);
            *(int4*)(KsB + r * 128 + (cb ^ sw)) = kv;
            int4 vv = *(const int4*)((const char*)(vbp + (size_t)r * T_SEQ + j0) + cb);
            *(int4*)(VtB + r * 128 + (cb ^ sw)) = vv;
        }
        __syncthreads();

        // S = Q K^T : 4 col-tiles x 2 k-steps
        f32x4 sa[4] = {zero4, zero4, zero4, zero4};
        #pragma unroll
        for (int nt = 0; nt < 4; ++nt) {
            const int row = nt * 16 + lr;
            const int sw  = (row & 7) << 4;
            bf16x8 bk0 = *(const bf16x8*)(KsB + row * 128 + ((lg * 16) ^ sw));
            bf16x8 bk1 = *(const bf16x8*)(KsB + row * 128 + ((64 + lg * 16) ^ sw));
            sa[nt] = __builtin_amdgcn_mfma_f32_16x16x32_bf16(aq0, bk0, sa[nt], 0, 0, 0);
            sa[nt] = __builtin_amdgcn_mfma_f32_16x16x32_bf16(aq1, bk1, sa[nt], 0, 0, 0);
        }

        // online softmax (rows live in 16-lane groups)
        #pragma unroll
        for (int r4 = 0; r4 < 4; ++r4) {
            const int gi = q0 + wave * 16 + lg * 4 + r4;
            float sv[4];
            float smax = -3e38f;
            #pragma unroll
            for (int nt = 0; nt < 4; ++nt) {
                const int gj = j0 + nt * 16 + lr;
                float s = (gj <= gi) ? sa[nt][r4] * 0.125f + rbs[gi - gj] : -3e38f;
                sv[nt] = s;
                smax = fmaxf(smax, s);
            }
            smax = fmaxf(smax, __shfl_xor(smax, 1));
            smax = fmaxf(smax, __shfl_xor(smax, 2));
            smax = fmaxf(smax, __shfl_xor(smax, 4));
            smax = fmaxf(smax, __shfl_xor(smax, 8));
            const float mnew  = fmaxf(m_r[r4], smax);
            const float alpha = __expf(m_r[r4] - mnew);
            float ps = 0.f;
            #pragma unroll
            for (int nt = 0; nt < 4; ++nt) {
                const float p = __expf(sv[nt] - mnew);
                sv[nt] = p;
                ps += p;
            }
            ps += __shfl_xor(ps, 1);
            ps += __shfl_xor(ps, 2);
            ps += __shfl_xor(ps, 4);
            ps += __shfl_xor(ps, 8);
            l_r[r4] = l_r[r4] * alpha + ps;
            m_r[r4] = mnew;
            #pragma unroll
            for (int dt = 0; dt < 4; ++dt) Oa[dt][r4] *= alpha;

            // write P row (bf16) into per-wave swizzled LDS buffer
            const int prow = lg * 4 + r4;
            char* pw = PsB[wave] + prow * 128;
            const int sw = (prow & 7) << 4;
            #pragma unroll
            for (int nt = 0; nt < 4; ++nt)
                *(ushort*)(pw + (((nt * 16 + lr) * 2) ^ sw)) = f2bf(sv[nt]);
        }
        __syncthreads();

        // O += P V : A-frags from PsB (rows = lr), B-frags from VtB
        bf16x8 ap0 = *(const bf16x8*)(PsB[wave] + lr * 128 + ((lg * 16) ^ ((lr & 7) << 4)));
        bf16x8 ap1 = *(const bf16x8*)(PsB[wave] + lr * 128 + ((64 + lg * 16) ^ ((lr & 7) << 4)));
        #pragma unroll
        for (int dt = 0; dt < 4; ++dt) {
            const int row = dt * 16 + lr;
            const int sw  = (row & 7) << 4;
            bf16x8 bv0 = *(const bf16x8*)(VtB + row * 128 + ((lg * 16) ^ sw));
            bf16x8 bv1 = *(const bf16x8*)(VtB + row * 128 + ((64 + lg * 16) ^ sw));
            Oa[dt] = __builtin_amdgcn_mfma_f32_16x16x32_bf16(ap0, bv0, Oa[dt], 0, 0, 0);
            Oa[dt] = __builtin_amdgcn_mfma_f32_16x16x32_bf16(ap1, bv1, Oa[dt], 0, 0, 0);
        }
        __syncthreads();   // Vt/Ps reads done before next stage overwrites
    }

    // y[b, t, h*64 + d] fp32
    #pragma unroll
    for (int r4 = 0; r4 < 4; ++r4) {
        const int t = q0 + wave * 16 + lg * 4 + r4;
        const float inv = 1.0f / l_r[r4];
        float* yr = y + ((size_t)(b * T_SEQ + t)) * CDIM + h * HD;
        #pragma unroll
        for (int dt = 0; dt < 4; ++dt) yr[dt * 16 + lr] = Oa[dt][r4] * inv;
    }
}

extern "C" void kernel_launch(void* const* d_in, const int* in_sizes, int n_in,
                              void* d_out, int out_size, void* d_ws, size_t ws_size,
                              hipStream_t stream)
{
    const float* x     = (const float*)d_in[0];   // [B,T,C]
    const float* Wqkv  = (const float*)d_in[1];   // [C,3C]
    const float* Wproj = (const float*)d_in[2];   // [C,C]
    const float* rb    = (const float*)d_in[3];   // [MAX_LEN,NH]
    float* out = (float*)d_out;                   // [B,T,C]

    const size_t per = (size_t)BATCH * NH * T_SEQ * HD;   // 8.39M elems
    ushort* qw = (ushort*)d_ws;                           // bf16 [B,H,T,64]
    ushort* kw = qw + per;                                // bf16 [B,H,T,64]
    ushort* vw = kw + per;                                // bf16 [B,H,64,T]
    float*  yb = (float*)(vw + per);                      // fp32 [B,T,C]
    if (ws_size < per * (3 * sizeof(ushort) + sizeof(float))) return;

    dim3 g1(MROWS / 128, (3 * CDIM) / 128);               // 64 x 24
    gemm128<1><<<g1, dim3(256), 0, stream>>>(x, Wqkv, nullptr, qw, kw, vw,
                                             MROWS, 3 * CDIM, CDIM);

    dim3 g2(T_SEQ / 64, BATCH * NH);                      // 32 x 64
    attn_mfma<<<g2, dim3(256), 0, stream>>>(qw, kw, vw, rb, yb);

    dim3 g3(MROWS / 128, CDIM / 128);                     // 64 x 8
    gemm128<0><<<g3, dim3(256), 0, stream>>>(yb, Wproj, out, nullptr, nullptr, nullptr,
                                             MROWS, CDIM, CDIM);
}

// Round 5
// 597.756 us; speedup vs baseline: 4.1812x; 1.8447x over previous
//
#include <hip/hip_runtime.h>
#include <hip/hip_bf16.h>

#define T_SEQ 2048
#define CDIM  1024
#define NH    16
#define HD    64
#define BATCH 4
#define MROWS (BATCH * T_SEQ)   // 8192

typedef __attribute__((ext_vector_type(8))) short bf16x8;
typedef __attribute__((ext_vector_type(4))) float f32x4;

__device__ __forceinline__ ushort f2bf(float f) {
    unsigned u = __float_as_uint(f);
    unsigned r = (u + 0x7fffu + ((u >> 16) & 1u)) >> 16;
    return (ushort)r;
}

// ---------------------------------------------------------------------------
// fp32 -> bf16 elementwise (x), vectorized 4-wide, grid-stride
// ---------------------------------------------------------------------------
__global__ __launch_bounds__(256)
void cvt_bf16(const float* __restrict__ in, ushort* __restrict__ out, int n4)
{
    const int stride = gridDim.x * blockDim.x;
    for (int i = blockIdx.x * blockDim.x + threadIdx.x; i < n4; i += stride) {
        float4 v = *(const float4*)&in[(size_t)i * 4];
        ushort4 o;
        o.x = f2bf(v.x); o.y = f2bf(v.y); o.z = f2bf(v.z); o.w = f2bf(v.w);
        *(ushort4*)&out[(size_t)i * 4] = o;
    }
}

// ---------------------------------------------------------------------------
// fp32 [R][C] -> bf16 [C][R] transpose+convert, 32x32 LDS tile
// ---------------------------------------------------------------------------
__global__ __launch_bounds__(256)
void transpose_cvt(const float* __restrict__ in, ushort* __restrict__ out,
                   int R, int C)
{
    __shared__ float t[32][33];
    const int c0 = blockIdx.x * 32, r0 = blockIdx.y * 32;
    const int tx = threadIdx.x & 31, ty = threadIdx.x >> 5;   // 8 rows/pass
    #pragma unroll
    for (int rr = 0; rr < 32; rr += 8)
        t[rr + ty][tx] = in[(size_t)(r0 + rr + ty) * C + c0 + tx];
    __syncthreads();
    #pragma unroll
    for (int rr = 0; rr < 32; rr += 8)
        out[(size_t)(c0 + rr + ty) * R + r0 + tx] = f2bf(t[tx][rr + ty]);
}

// ---------------------------------------------------------------------------
// bf16 MFMA GEMM, 128x128 tile, BK=64, 256 threads = 4 waves (2x2), each wave
// owns a 64x64 output block (4x4 frags of 16x16). A[M][K] bf16 row-major,
// Bt[N][K] bf16 row-major (B transposed). LDS tiles [128 rows][64 bf16=128B]
// with XOR swizzle byte ^= (row&7)<<4 -> conflict-free b128 frag reads
// (same verified pattern as attn_mfma).
// SCATTER=0: C fp32 [M][N].
// SCATTER=1: N==3*CDIM, scatter bf16 into q/k [B,H,T,64] and vT [B,H,64,T].
// ---------------------------------------------------------------------------
template<int SCATTER>
__global__ __launch_bounds__(256)
void gemm_mfma(const ushort* __restrict__ A, const ushort* __restrict__ Bt,
               float* __restrict__ C0, ushort* __restrict__ Q0,
               ushort* __restrict__ K0, ushort* __restrict__ V0,
               int M, int N, int K)
{
    __shared__ __align__(16) char Asm[128 * 128];
    __shared__ __align__(16) char Bsm[128 * 128];

    const int tid  = threadIdx.x;
    const int wave = tid >> 6;
    const int lane = tid & 63;
    const int lr   = lane & 15;
    const int lg   = lane >> 4;
    const int wr   = wave >> 1;      // wave m-block (0..1)
    const int wc   = wave & 1;       // wave n-block (0..1)
    const int m0   = blockIdx.x * 128;
    const int n0   = blockIdx.y * 128;

    const int sr  = tid >> 1;              // stage row 0..127
    const int sh  = (tid & 1) * 64;        // stage half (bytes)
    const int ssw = (sr & 7) << 4;

    const f32x4 zero4 = {0.f, 0.f, 0.f, 0.f};
    f32x4 acc[4][4];
    #pragma unroll
    for (int i = 0; i < 4; ++i)
        #pragma unroll
        for (int j = 0; j < 4; ++j) acc[i][j] = zero4;

    const char* Ag = (const char*)(A + (size_t)(m0 + sr) * K) + sh;
    const char* Bg = (const char*)(Bt + (size_t)(n0 + sr) * K) + sh;

    for (int k0 = 0; k0 < K; k0 += 64) {
        int4 av[4], bv[4];
        #pragma unroll
        for (int i = 0; i < 4; ++i) {
            av[i] = *(const int4*)(Ag + (size_t)k0 * 2 + i * 16);
            bv[i] = *(const int4*)(Bg + (size_t)k0 * 2 + i * 16);
        }
        __syncthreads();               // previous iteration's frag reads done
        #pragma unroll
        for (int i = 0; i < 4; ++i) {
            *(int4*)(Asm + sr * 128 + ((sh + i * 16) ^ ssw)) = av[i];
            *(int4*)(Bsm + sr * 128 + ((sh + i * 16) ^ ssw)) = bv[i];
        }
        __syncthreads();               // tiles ready

        #pragma unroll
        for (int ks = 0; ks < 2; ++ks) {
            bf16x8 af[4], bf[4];
            #pragma unroll
            for (int mt = 0; mt < 4; ++mt) {
                const int row = wr * 64 + mt * 16 + lr;
                af[mt] = *(const bf16x8*)(Asm + row * 128 +
                         ((ks * 64 + lg * 16) ^ ((row & 7) << 4)));
            }
            #pragma unroll
            for (int nt = 0; nt < 4; ++nt) {
                const int row = wc * 64 + nt * 16 + lr;
                bf[nt] = *(const bf16x8*)(Bsm + row * 128 +
                         ((ks * 64 + lg * 16) ^ ((row & 7) << 4)));
            }
            #pragma unroll
            for (int mt = 0; mt < 4; ++mt)
                #pragma unroll
                for (int nt = 0; nt < 4; ++nt)
                    acc[mt][nt] = __builtin_amdgcn_mfma_f32_16x16x32_bf16(
                        af[mt], bf[nt], acc[mt][nt], 0, 0, 0);
        }
    }

    if (SCATTER == 0) {
        #pragma unroll
        for (int mt = 0; mt < 4; ++mt)
            #pragma unroll
            for (int r4 = 0; r4 < 4; ++r4) {
                const int m = m0 + wr * 64 + mt * 16 + lg * 4 + r4;
                float* cr = C0 + (size_t)m * N + n0 + wc * 64;
                #pragma unroll
                for (int nt = 0; nt < 4; ++nt)
                    cr[nt * 16 + lr] = acc[mt][nt][r4];
            }
    } else {
        const int which = n0 >> 10;            // 0=q 1=k 2=v
        const int nn = n0 & (CDIM - 1);
        const int h  = (nn >> 6) + wc;         // wave's 64 cols = one head
        const int b  = m0 >> 11;
        const int t0 = (m0 & (T_SEQ - 1)) + wr * 64;
        if (which < 2) {
            ushort* dst = (which == 0) ? Q0 : K0;   // [B,H,T,64]
            ushort* base = dst + (size_t)(b * NH + h) * T_SEQ * HD;
            #pragma unroll
            for (int mt = 0; mt < 4; ++mt)
                #pragma unroll
                for (int r4 = 0; r4 < 4; ++r4) {
                    const int t = t0 + mt * 16 + lg * 4 + r4;
                    ushort* tr = base + (size_t)t * HD;
                    #pragma unroll
                    for (int nt = 0; nt < 4; ++nt)
                        tr[nt * 16 + lr] = f2bf(acc[mt][nt][r4]);
                }
        } else {
            // vT [B,H,64,T]: lane owns col d, 4 consecutive t per frag
            ushort* base = V0 + (size_t)(b * NH + h) * HD * T_SEQ;
            #pragma unroll
            for (int mt = 0; mt < 4; ++mt) {
                const int t = t0 + mt * 16 + lg * 4;
                #pragma unroll
                for (int nt = 0; nt < 4; ++nt) {
                    const int d = nt * 16 + lr;
                    ushort4 w4;
                    w4.x = f2bf(acc[mt][nt][0]);
                    w4.y = f2bf(acc[mt][nt][1]);
                    w4.z = f2bf(acc[mt][nt][2]);
                    w4.w = f2bf(acc[mt][nt][3]);
                    *(ushort4*)&base[(size_t)d * T_SEQ + t] = w4;
                }
            }
        }
    }
}

// ---------------------------------------------------------------------------
// Flash attention, bf16 MFMA (16x16x32), causal + rel-pos bias (verified r4).
// Output y now written as bf16 [B,T,C] to feed the proj GEMM directly.
// ---------------------------------------------------------------------------
__global__ __launch_bounds__(256)
void attn_mfma(const ushort* __restrict__ qb, const ushort* __restrict__ kb,
               const ushort* __restrict__ vb, const float* __restrict__ rb,
               ushort* __restrict__ y)
{
    __shared__ __align__(16) char KsB[64 * 128];
    __shared__ __align__(16) char VtB[64 * 128];
    __shared__ __align__(16) char PsB[4][16 * 128];
    __shared__ float rbs[T_SEQ];

    const int tid  = threadIdx.x;
    const int wave = tid >> 6;
    const int lane = tid & 63;
    const int lr   = lane & 15;
    const int lg   = lane >> 4;
    const int bh   = blockIdx.y;
    const int h    = bh & (NH - 1);
    const int b    = bh >> 4;
    const int q0   = blockIdx.x * 64;

    for (int i = tid; i < q0 + 64; i += 256) rbs[i] = rb[(size_t)i * NH + h];

    const ushort* qrow = qb + ((size_t)bh * T_SEQ + q0 + wave * 16 + lr) * HD;
    const bf16x8 aq0 = *(const bf16x8*)(qrow + lg * 8);
    const bf16x8 aq1 = *(const bf16x8*)(qrow + 32 + lg * 8);

    const f32x4 zero4 = {0.f, 0.f, 0.f, 0.f};
    f32x4 Oa[4] = {zero4, zero4, zero4, zero4};
    float m_r[4], l_r[4];
    #pragma unroll
    for (int r4 = 0; r4 < 4; ++r4) { m_r[r4] = -3e38f; l_r[r4] = 0.f; }

    const ushort* kbp = kb + (size_t)bh * T_SEQ * HD;
    const ushort* vbp = vb + (size_t)bh * HD * T_SEQ;

    const int nkt = blockIdx.x + 1;
    for (int kt = 0; kt < nkt; ++kt) {
        const int j0 = kt * 64;

        #pragma unroll
        for (int s = 0; s < 2; ++s) {
            const int cid = tid + s * 256;
            const int r  = cid >> 3;
            const int cb = (cid & 7) * 16;
            const int sw = (r & 7) << 4;
            int4 kv = *(const int4*)((const char*)(kbp + (size_t)(j0 + r) * HD) + cb);
            *(int4*)(KsB + r * 128 + (cb ^ sw)) = kv;
            int4 vv = *(const int4*)((const char*)(vbp + (size_t)r * T_SEQ + j0) + cb);
            *(int4*)(VtB + r * 128 + (cb ^ sw)) = vv;
        }
        __syncthreads();

        f32x4 sa[4] = {zero4, zero4, zero4, zero4};
        #pragma unroll
        for (int nt = 0; nt < 4; ++nt) {
            const int row = nt * 16 + lr;
            const int sw  = (row & 7) << 4;
            bf16x8 bk0 = *(const bf16x8*)(KsB + row * 128 + ((lg * 16) ^ sw));
            bf16x8 bk1 = *(const bf16x8*)(KsB + row * 128 + ((64 + lg * 16) ^ sw));
            sa[nt] = __builtin_amdgcn_mfma_f32_16x16x32_bf16(aq0, bk0, sa[nt], 0, 0, 0);
            sa[nt] = __builtin_amdgcn_mfma_f32_16x16x32_bf16(aq1, bk1, sa[nt], 0, 0, 0);
        }

        #pragma unroll
        for (int r4 = 0; r4 < 4; ++r4) {
            const int gi = q0 + wave * 16 + lg * 4 + r4;
            float sv[4];
            float smax = -3e38f;
            #pragma unroll
            for (int nt = 0; nt < 4; ++nt) {
                const int gj = j0 + nt * 16 + lr;
                float s = (gj <= gi) ? sa[nt][r4] * 0.125f + rbs[gi - gj] : -3e38f;
                sv[nt] = s;
                smax = fmaxf(smax, s);
            }
            smax = fmaxf(smax, __shfl_xor(smax, 1));
            smax = fmaxf(smax, __shfl_xor(smax, 2));
            smax = fmaxf(smax, __shfl_xor(smax, 4));
            smax = fmaxf(smax, __shfl_xor(smax, 8));
            const float mnew  = fmaxf(m_r[r4], smax);
            const float alpha = __expf(m_r[r4] - mnew);
            float ps = 0.f;
            #pragma unroll
            for (int nt = 0; nt < 4; ++nt) {
                const float p = __expf(sv[nt] - mnew);
                sv[nt] = p;
                ps += p;
            }
            ps += __shfl_xor(ps, 1);
            ps += __shfl_xor(ps, 2);
            ps += __shfl_xor(ps, 4);
            ps += __shfl_xor(ps, 8);
            l_r[r4] = l_r[r4] * alpha + ps;
            m_r[r4] = mnew;
            #pragma unroll
            for (int dt = 0; dt < 4; ++dt) Oa[dt][r4] *= alpha;

            const int prow = lg * 4 + r4;
            char* pw = PsB[wave] + prow * 128;
            const int sw = (prow & 7) << 4;
            #pragma unroll
            for (int nt = 0; nt < 4; ++nt)
                *(ushort*)(pw + (((nt * 16 + lr) * 2) ^ sw)) = f2bf(sv[nt]);
        }
        __syncthreads();

        bf16x8 ap0 = *(const bf16x8*)(PsB[wave] + lr * 128 + ((lg * 16) ^ ((lr & 7) << 4)));
        bf16x8 ap1 = *(const bf16x8*)(PsB[wave] + lr * 128 + ((64 + lg * 16) ^ ((lr & 7) << 4)));
        #pragma unroll
        for (int dt = 0; dt < 4; ++dt) {
            const int row = dt * 16 + lr;
            const int sw  = (row & 7) << 4;
            bf16x8 bv0 = *(const bf16x8*)(VtB + row * 128 + ((lg * 16) ^ sw));
            bf16x8 bv1 = *(const bf16x8*)(VtB + row * 128 + ((64 + lg * 16) ^ sw));
            Oa[dt] = __builtin_amdgcn_mfma_f32_16x16x32_bf16(ap0, bv0, Oa[dt], 0, 0, 0);
            Oa[dt] = __builtin_amdgcn_mfma_f32_16x16x32_bf16(ap1, bv1, Oa[dt], 0, 0, 0);
        }
        __syncthreads();
    }

    #pragma unroll
    for (int r4 = 0; r4 < 4; ++r4) {
        const int t = q0 + wave * 16 + lg * 4 + r4;
        const float inv = 1.0f / l_r[r4];
        ushort* yr = y + ((size_t)(b * T_SEQ + t)) * CDIM + h * HD;
        #pragma unroll
        for (int dt = 0; dt < 4; ++dt) yr[dt * 16 + lr] = f2bf(Oa[dt][r4] * inv);
    }
}

extern "C" void kernel_launch(void* const* d_in, const int* in_sizes, int n_in,
                              void* d_out, int out_size, void* d_ws, size_t ws_size,
                              hipStream_t stream)
{
    const float* x     = (const float*)d_in[0];   // [B,T,C]
    const float* Wqkv  = (const float*)d_in[1];   // [C,3C]
    const float* Wproj = (const float*)d_in[2];   // [C,C]
    const float* rb    = (const float*)d_in[3];   // [MAX_LEN,NH]
    float* out = (float*)d_out;                   // [B,T,C] fp32

    const size_t per = (size_t)BATCH * NH * T_SEQ * HD;   // 8.39M elems
    ushort* xb  = (ushort*)d_ws;                          // bf16 [M][C]
    ushort* wqT = xb + per;                               // bf16 [3C][C]
    ushort* wpT = wqT + (size_t)3 * CDIM * CDIM;          // bf16 [C][C]
    ushort* qw  = wpT + (size_t)CDIM * CDIM;              // bf16 [B,H,T,64]
    ushort* kw  = qw + per;
    ushort* vw  = kw + per;                               // bf16 [B,H,64,T]
    ushort* yb  = vw + per;                               // bf16 [B,T,C]
    const size_t need = (per * 5 + (size_t)4 * CDIM * CDIM) * sizeof(ushort);
    if (ws_size < need) return;

    cvt_bf16<<<2048, 256, 0, stream>>>(x, xb, (int)(per / 4));
    transpose_cvt<<<dim3(3 * CDIM / 32, CDIM / 32), 256, 0, stream>>>(Wqkv, wqT, CDIM, 3 * CDIM);
    transpose_cvt<<<dim3(CDIM / 32, CDIM / 32), 256, 0, stream>>>(Wproj, wpT, CDIM, CDIM);

    dim3 g1(MROWS / 128, (3 * CDIM) / 128);               // 64 x 24
    gemm_mfma<1><<<g1, dim3(256), 0, stream>>>(xb, wqT, nullptr, qw, kw, vw,
                                               MROWS, 3 * CDIM, CDIM);

    dim3 g2(T_SEQ / 64, BATCH * NH);                      // 32 x 64
    attn_mfma<<<g2, dim3(256), 0, stream>>>(qw, kw, vw, rb, yb);

    dim3 g3(MROWS / 128, CDIM / 128);                     // 64 x 8
    gemm_mfma<0><<<g3, dim3(256), 0, stream>>>(yb, wpT, out, nullptr, nullptr, nullptr,
                                               MROWS, CDIM, CDIM);
}

// Round 9
// 451.972 us; speedup vs baseline: 5.5298x; 1.3226x over previous
//
#include <hip/hip_runtime.h>
#include <hip/hip_bf16.h>

#define T_SEQ 2048
#define CDIM  1024
#define NH    16
#define HD    64
#define BATCH 4
#define MROWS (BATCH * T_SEQ)   // 8192
#define QSCALE 0.18033688011112042f   // 0.125 * log2(e)
#define LOG2E  1.4426950408889634f

typedef __attribute__((ext_vector_type(8))) short bf16x8;
typedef __attribute__((ext_vector_type(4))) float f32x4;

__device__ __forceinline__ ushort f2bf(float f) {
    unsigned u = __float_as_uint(f);
    unsigned r = (u + 0x7fffu + ((u >> 16) & 1u)) >> 16;
    return (ushort)r;
}

// ---------------------------------------------------------------------------
// fp32 -> bf16 elementwise (x), vectorized 4-wide, grid-stride
// ---------------------------------------------------------------------------
__global__ __launch_bounds__(256)
void cvt_bf16(const float* __restrict__ in, ushort* __restrict__ out, int n4)
{
    const int stride = gridDim.x * blockDim.x;
    for (int i = blockIdx.x * blockDim.x + threadIdx.x; i < n4; i += stride) {
        float4 v = *(const float4*)&in[(size_t)i * 4];
        ushort4 o;
        o.x = f2bf(v.x); o.y = f2bf(v.y); o.z = f2bf(v.z); o.w = f2bf(v.w);
        *(ushort4*)&out[(size_t)i * 4] = o;
    }
}

// ---------------------------------------------------------------------------
// fp32 [R][C] -> bf16 [C][R] transpose+convert, 32x32 LDS tile
// ---------------------------------------------------------------------------
__global__ __launch_bounds__(256)
void transpose_cvt(const float* __restrict__ in, ushort* __restrict__ out,
                   int R, int C)
{
    __shared__ float t[32][33];
    const int c0 = blockIdx.x * 32, r0 = blockIdx.y * 32;
    const int tx = threadIdx.x & 31, ty = threadIdx.x >> 5;   // 8 rows/pass
    #pragma unroll
    for (int rr = 0; rr < 32; rr += 8)
        t[rr + ty][tx] = in[(size_t)(r0 + rr + ty) * C + c0 + tx];
    __syncthreads();
    #pragma unroll
    for (int rr = 0; rr < 32; rr += 8)
        out[(size_t)(c0 + rr + ty) * R + r0 + tx] = f2bf(t[tx][rr + ty]);
}

// ---------------------------------------------------------------------------
// bf16 MFMA GEMM, 128x128 tile, BK=64, 256 threads = 4 waves (2x2).
// A[M][K] bf16 row-major, Bt[N][K] bf16 row-major (B transposed).
// LDS XOR swizzle byte ^= (row&7)<<4 -> conflict-free b128 reads (verified r5:
// SQ_LDS_BANK_CONFLICT == 0).
// SCATTER=0: C fp32 [M][N].
// SCATTER=1: N==3*CDIM, scatter bf16 q (pre-scaled by QSCALE) / k [B,H,T,64],
//            vT [B,H,64,T].
// ---------------------------------------------------------------------------
template<int SCATTER>
__global__ __launch_bounds__(256)
void gemm_mfma(const ushort* __restrict__ A, const ushort* __restrict__ Bt,
               float* __restrict__ C0, ushort* __restrict__ Q0,
               ushort* __restrict__ K0, ushort* __restrict__ V0,
               int M, int N, int K)
{
    __shared__ __align__(16) char Asm[128 * 128];
    __shared__ __align__(16) char Bsm[128 * 128];

    const int tid  = threadIdx.x;
    const int wave = tid >> 6;
    const int lane = tid & 63;
    const int lr   = lane & 15;
    const int lg   = lane >> 4;
    const int wr   = wave >> 1;
    const int wc   = wave & 1;
    const int m0   = blockIdx.x * 128;
    const int n0   = blockIdx.y * 128;

    const int sr  = tid >> 1;
    const int sh  = (tid & 1) * 64;
    const int ssw = (sr & 7) << 4;

    const f32x4 zero4 = {0.f, 0.f, 0.f, 0.f};
    f32x4 acc[4][4];
    #pragma unroll
    for (int i = 0; i < 4; ++i)
        #pragma unroll
        for (int j = 0; j < 4; ++j) acc[i][j] = zero4;

    const char* Ag = (const char*)(A + (size_t)(m0 + sr) * K) + sh;
    const char* Bg = (const char*)(Bt + (size_t)(n0 + sr) * K) + sh;

    for (int k0 = 0; k0 < K; k0 += 64) {
        int4 av[4], bv[4];
        #pragma unroll
        for (int i = 0; i < 4; ++i) {
            av[i] = *(const int4*)(Ag + (size_t)k0 * 2 + i * 16);
            bv[i] = *(const int4*)(Bg + (size_t)k0 * 2 + i * 16);
        }
        __syncthreads();
        #pragma unroll
        for (int i = 0; i < 4; ++i) {
            *(int4*)(Asm + sr * 128 + ((sh + i * 16) ^ ssw)) = av[i];
            *(int4*)(Bsm + sr * 128 + ((sh + i * 16) ^ ssw)) = bv[i];
        }
        __syncthreads();

        #pragma unroll
        for (int ks = 0; ks < 2; ++ks) {
            bf16x8 af[4], bf[4];
            #pragma unroll
            for (int mt = 0; mt < 4; ++mt) {
                const int row = wr * 64 + mt * 16 + lr;
                af[mt] = *(const bf16x8*)(Asm + row * 128 +
                         ((ks * 64 + lg * 16) ^ ((row & 7) << 4)));
            }
            #pragma unroll
            for (int nt = 0; nt < 4; ++nt) {
                const int row = wc * 64 + nt * 16 + lr;
                bf[nt] = *(const bf16x8*)(Bsm + row * 128 +
                         ((ks * 64 + lg * 16) ^ ((row & 7) << 4)));
            }
            #pragma unroll
            for (int mt = 0; mt < 4; ++mt)
                #pragma unroll
                for (int nt = 0; nt < 4; ++nt)
                    acc[mt][nt] = __builtin_amdgcn_mfma_f32_16x16x32_bf16(
                        af[mt], bf[nt], acc[mt][nt], 0, 0, 0);
        }
    }

    if (SCATTER == 0) {
        #pragma unroll
        for (int mt = 0; mt < 4; ++mt)
            #pragma unroll
            for (int r4 = 0; r4 < 4; ++r4) {
                const int m = m0 + wr * 64 + mt * 16 + lg * 4 + r4;
                float* cr = C0 + (size_t)m * N + n0 + wc * 64;
                #pragma unroll
                for (int nt = 0; nt < 4; ++nt)
                    cr[nt * 16 + lr] = acc[mt][nt][r4];
            }
    } else {
        const int which = n0 >> 10;            // 0=q 1=k 2=v
        const int nn = n0 & (CDIM - 1);
        const int h  = (nn >> 6) + wc;
        const int b  = m0 >> 11;
        const int t0 = (m0 & (T_SEQ - 1)) + wr * 64;
        if (which < 2) {
            const float qs = (which == 0) ? QSCALE : 1.0f;  // fold 0.125*log2e into q
            ushort* dst = (which == 0) ? Q0 : K0;   // [B,H,T,64]
            ushort* base = dst + (size_t)(b * NH + h) * T_SEQ * HD;
            #pragma unroll
            for (int mt = 0; mt < 4; ++mt)
                #pragma unroll
                for (int r4 = 0; r4 < 4; ++r4) {
                    const int t = t0 + mt * 16 + lg * 4 + r4;
                    ushort* tr = base + (size_t)t * HD;
                    #pragma unroll
                    for (int nt = 0; nt < 4; ++nt)
                        tr[nt * 16 + lr] = f2bf(acc[mt][nt][r4] * qs);
                }
        } else {
            ushort* base = V0 + (size_t)(b * NH + h) * HD * T_SEQ;
            #pragma unroll
            for (int mt = 0; mt < 4; ++mt) {
                const int t = t0 + mt * 16 + lg * 4;
                #pragma unroll
                for (int nt = 0; nt < 4; ++nt) {
                    const int d = nt * 16 + lr;
                    ushort4 w4;
                    w4.x = f2bf(acc[mt][nt][0]);
                    w4.y = f2bf(acc[mt][nt][1]);
                    w4.z = f2bf(acc[mt][nt][2]);
                    w4.w = f2bf(acc[mt][nt][3]);
                    *(ushort4*)&base[(size_t)d * T_SEQ + t] = w4;
                }
            }
        }
    }
}

// ---------------------------------------------------------------------------
// Flash attention, bf16 MFMA, causal + rel-bias. 512 threads = 8 waves, each
// wave owns 16 q-rows (QBLK=128). exp2-domain softmax (q pre-scaled, bias
// pre-scaled by log2e). Async-stage split: next tile's global loads issued
// before compute, LDS write after barrier. 2 barriers per k-tile (P buffer is
// wave-private). Big q-tiles dispatched first.
// ---------------------------------------------------------------------------
__global__ __launch_bounds__(512, 4)
void attn_mfma(const ushort* __restrict__ qb, const ushort* __restrict__ kb,
               const ushort* __restrict__ vb, const float* __restrict__ rb,
               ushort* __restrict__ y)
{
    __shared__ __align__(16) char KsB[64 * 128];      // 8 KB
    __shared__ __align__(16) char VtB[64 * 128];      // 8 KB
    __shared__ __align__(16) char PsB[8][16 * 128];   // 16 KB
    __shared__ float rbs[T_SEQ];                      // 8 KB (scaled by log2e)

    const int tid  = threadIdx.x;
    const int wave = tid >> 6;
    const int lane = tid & 63;
    const int lr   = lane & 15;
    const int lg   = lane >> 4;
    const int bh   = blockIdx.x;          // bh fastest; big q-tiles first in y
    const int h    = bh & (NH - 1);
    const int b    = bh >> 4;
    const int qt   = (int)gridDim.y - 1 - (int)blockIdx.y;
    const int q0   = qt * 128;

    for (int i = tid; i < q0 + 128; i += 512)
        rbs[i] = rb[(size_t)i * NH + h] * LOG2E;

    const ushort* qrow = qb + ((size_t)bh * T_SEQ + q0 + wave * 16 + lr) * HD;
    const bf16x8 aq0 = *(const bf16x8*)(qrow + lg * 8);
    const bf16x8 aq1 = *(const bf16x8*)(qrow + 32 + lg * 8);

    const f32x4 zero4 = {0.f, 0.f, 0.f, 0.f};
    f32x4 Oa[4] = {zero4, zero4, zero4, zero4};
    float m_r[4], l_r[4];
    #pragma unroll
    for (int r4 = 0; r4 < 4; ++r4) { m_r[r4] = -3e38f; l_r[r4] = 0.f; }

    const char* kbp = (const char*)(kb + (size_t)bh * T_SEQ * HD);
    const char* vbp = (const char*)(vb + (size_t)bh * HD * T_SEQ);

    // staging: 512 threads x 16 B cover one 64x128B tile exactly
    const int r_st  = tid >> 3;
    const int cb    = (tid & 7) * 16;
    const int sw_st = (r_st & 7) << 4;

    const int nkt = 2 * (qt + 1);

    int4 kreg = *(const int4*)(kbp + (size_t)r_st * HD * 2 + cb);
    int4 vreg = *(const int4*)(vbp + (size_t)r_st * T_SEQ * 2 + cb);

    for (int kt = 0; kt < nkt; ++kt) {
        const int j0 = kt * 64;
        __syncthreads();                  // all waves done reading prev tile
        *(int4*)(KsB + r_st * 128 + (cb ^ sw_st)) = kreg;
        *(int4*)(VtB + r_st * 128 + (cb ^ sw_st)) = vreg;
        __syncthreads();                  // tile ready
        if (kt + 1 < nkt) {               // prefetch next tile (hides HBM lat)
            const int j1 = j0 + 64;
            kreg = *(const int4*)(kbp + (size_t)(j1 + r_st) * HD * 2 + cb);
            vreg = *(const int4*)(vbp + ((size_t)r_st * T_SEQ + j1) * 2 + cb);
        }

        // S = Q K^T (q pre-scaled: S already in exp2 domain after bias add)
        f32x4 sa[4] = {zero4, zero4, zero4, zero4};
        #pragma unroll
        for (int nt = 0; nt < 4; ++nt) {
            const int row = nt * 16 + lr;
            const int sw  = (row & 7) << 4;
            bf16x8 bk0 = *(const bf16x8*)(KsB + row * 128 + ((lg * 16) ^ sw));
            bf16x8 bk1 = *(const bf16x8*)(KsB + row * 128 + ((64 + lg * 16) ^ sw));
            sa[nt] = __builtin_amdgcn_mfma_f32_16x16x32_bf16(aq0, bk0, sa[nt], 0, 0, 0);
            sa[nt] = __builtin_amdgcn_mfma_f32_16x16x32_bf16(aq1, bk1, sa[nt], 0, 0, 0);
        }

        // online softmax, exp2 domain
        #pragma unroll
        for (int r4 = 0; r4 < 4; ++r4) {
            const int gi = q0 + wave * 16 + lg * 4 + r4;
            float sv[4];
            float smax = -3e38f;
            #pragma unroll
            for (int nt = 0; nt < 4; ++nt) {
                const int gj = j0 + nt * 16 + lr;
                float s = (gj <= gi) ? sa[nt][r4] + rbs[gi - gj] : -3e38f;
                sv[nt] = s;
                smax = fmaxf(smax, s);
            }
            smax = fmaxf(smax, __shfl_xor(smax, 1));
            smax = fmaxf(smax, __shfl_xor(smax, 2));
            smax = fmaxf(smax, __shfl_xor(smax, 4));
            smax = fmaxf(smax, __shfl_xor(smax, 8));
            const float mnew  = fmaxf(m_r[r4], smax);
            const float alpha = exp2f(m_r[r4] - mnew);
            float ps = 0.f;
            #pragma unroll
            for (int nt = 0; nt < 4; ++nt) {
                const float p = exp2f(sv[nt] - mnew);
                sv[nt] = p;
                ps += p;
            }
            ps += __shfl_xor(ps, 1);
            ps += __shfl_xor(ps, 2);
            ps += __shfl_xor(ps, 4);
            ps += __shfl_xor(ps, 8);
            l_r[r4] = l_r[r4] * alpha + ps;
            m_r[r4] = mnew;
            #pragma unroll
            for (int dt = 0; dt < 4; ++dt) Oa[dt][r4] *= alpha;

            const int prow = lg * 4 + r4;
            char* pw = PsB[wave] + prow * 128;
            const int swp = (prow & 7) << 4;
            #pragma unroll
            for (int nt = 0; nt < 4; ++nt)
                *(ushort*)(pw + (((nt * 16 + lr) * 2) ^ swp)) = f2bf(sv[nt]);
        }
        // no barrier: PsB is wave-private (lgkmcnt orders), VtB stable

        bf16x8 ap0 = *(const bf16x8*)(PsB[wave] + lr * 128 + ((lg * 16) ^ ((lr & 7) << 4)));
        bf16x8 ap1 = *(const bf16x8*)(PsB[wave] + lr * 128 + ((64 + lg * 16) ^ ((lr & 7) << 4)));
        #pragma unroll
        for (int dt = 0; dt < 4; ++dt) {
            const int row = dt * 16 + lr;
            const int sw  = (row & 7) << 4;
            bf16x8 bv0 = *(const bf16x8*)(VtB + row * 128 + ((lg * 16) ^ sw));
            bf16x8 bv1 = *(const bf16x8*)(VtB + row * 128 + ((64 + lg * 16) ^ sw));
            Oa[dt] = __builtin_amdgcn_mfma_f32_16x16x32_bf16(ap0, bv0, Oa[dt], 0, 0, 0);
            Oa[dt] = __builtin_amdgcn_mfma_f32_16x16x32_bf16(ap1, bv1, Oa[dt], 0, 0, 0);
        }
    }

    #pragma unroll
    for (int r4 = 0; r4 < 4; ++r4) {
        const int t = q0 + wave * 16 + lg * 4 + r4;
        const float inv = 1.0f / l_r[r4];
        ushort* yr = y + ((size_t)(b * T_SEQ + t)) * CDIM + h * HD;
        #pragma unroll
        for (int dt = 0; dt < 4; ++dt) yr[dt * 16 + lr] = f2bf(Oa[dt][r4] * inv);
    }
}

extern "C" void kernel_launch(void* const* d_in, const int* in_sizes, int n_in,
                              void* d_out, int out_size, void* d_ws, size_t ws_size,
                              hipStream_t stream)
{
    const float* x     = (const float*)d_in[0];   // [B,T,C]
    const float* Wqkv  = (const float*)d_in[1];   // [C,3C]
    const float* Wproj = (const float*)d_in[2];   // [C,C]
    const float* rb    = (const float*)d_in[3];   // [MAX_LEN,NH]
    float* out = (float*)d_out;                   // [B,T,C] fp32

    const size_t per = (size_t)BATCH * NH * T_SEQ * HD;   // 8.39M elems
    ushort* xb  = (ushort*)d_ws;                          // bf16 [M][C]
    ushort* wqT = xb + per;                               // bf16 [3C][C]
    ushort* wpT = wqT + (size_t)3 * CDIM * CDIM;          // bf16 [C][C]
    ushort* qw  = wpT + (size_t)CDIM * CDIM;              // bf16 [B,H,T,64] (pre-scaled)
    ushort* kw  = qw + per;
    ushort* vw  = kw + per;                               // bf16 [B,H,64,T]
    ushort* yb  = vw + per;                               // bf16 [B,T,C]
    const size_t need = (per * 5 + (size_t)4 * CDIM * CDIM) * sizeof(ushort);
    if (ws_size < need) return;

    cvt_bf16<<<2048, 256, 0, stream>>>(x, xb, (int)(per / 4));
    transpose_cvt<<<dim3(3 * CDIM / 32, CDIM / 32), 256, 0, stream>>>(Wqkv, wqT, CDIM, 3 * CDIM);
    transpose_cvt<<<dim3(CDIM / 32, CDIM / 32), 256, 0, stream>>>(Wproj, wpT, CDIM, CDIM);

    dim3 g1(MROWS / 128, (3 * CDIM) / 128);               // 64 x 24
    gemm_mfma<1><<<g1, dim3(256), 0, stream>>>(xb, wqT, nullptr, qw, kw, vw,
                                               MROWS, 3 * CDIM, CDIM);

    dim3 g2(BATCH * NH, T_SEQ / 128);                     // 64 x 16, big-first in y
    attn_mfma<<<g2, dim3(512), 0, stream>>>(qw, kw, vw, rb, yb);

    dim3 g3(MROWS / 128, CDIM / 128);                     // 64 x 8
    gemm_mfma<0><<<g3, dim3(256), 0, stream>>>(yb, wpT, out, nullptr, nullptr, nullptr,
                                               MROWS, CDIM, CDIM);
}

// Round 10
// 450.699 us; speedup vs baseline: 5.5454x; 1.0028x over previous
//
#include <hip/hip_runtime.h>
#include <hip/hip_bf16.h>

#define T_SEQ 2048
#define CDIM  1024
#define NH    16
#define HD    64
#define BATCH 4
#define MROWS (BATCH * T_SEQ)   // 8192
#define QSCALE 0.18033688011112042f   // 0.125 * log2(e)
#define LOG2E  1.4426950408889634f

typedef __attribute__((ext_vector_type(8))) short bf16x8;
typedef __attribute__((ext_vector_type(4))) float f32x4;

__device__ __forceinline__ ushort f2bf(float f) {
    unsigned u = __float_as_uint(f);
    unsigned r = (u + 0x7fffu + ((u >> 16) & 1u)) >> 16;
    return (ushort)r;
}

// ---------------------------------------------------------------------------
// fp32 -> bf16 elementwise (x), vectorized 4-wide, grid-stride
// ---------------------------------------------------------------------------
__global__ __launch_bounds__(256)
void cvt_bf16(const float* __restrict__ in, ushort* __restrict__ out, int n4)
{
    const int stride = gridDim.x * blockDim.x;
    for (int i = blockIdx.x * blockDim.x + threadIdx.x; i < n4; i += stride) {
        float4 v = *(const float4*)&in[(size_t)i * 4];
        ushort4 o;
        o.x = f2bf(v.x); o.y = f2bf(v.y); o.z = f2bf(v.z); o.w = f2bf(v.w);
        *(ushort4*)&out[(size_t)i * 4] = o;
    }
}

// ---------------------------------------------------------------------------
// fp32 [R][C] -> bf16 [C][R] transpose+convert, 32x32 LDS tile
// ---------------------------------------------------------------------------
__global__ __launch_bounds__(256)
void transpose_cvt(const float* __restrict__ in, ushort* __restrict__ out,
                   int R, int C)
{
    __shared__ float t[32][33];
    const int c0 = blockIdx.x * 32, r0 = blockIdx.y * 32;
    const int tx = threadIdx.x & 31, ty = threadIdx.x >> 5;   // 8 rows/pass
    #pragma unroll
    for (int rr = 0; rr < 32; rr += 8)
        t[rr + ty][tx] = in[(size_t)(r0 + rr + ty) * C + c0 + tx];
    __syncthreads();
    #pragma unroll
    for (int rr = 0; rr < 32; rr += 8)
        out[(size_t)(c0 + rr + ty) * R + r0 + tx] = f2bf(t[tx][rr + ty]);
}

// ---------------------------------------------------------------------------
// bf16 MFMA GEMM, 128x128 tile, BK=64, 256 threads = 4 waves (2x2).
// A[M][K] bf16 row-major, Bt[N][K] bf16 row-major (B transposed).
// LDS XOR swizzle byte ^= (row&7)<<4 -> conflict-free b128 reads (verified r5:
// SQ_LDS_BANK_CONFLICT == 0).
// SCATTER=0: C fp32 [M][N] direct.
// SCATTER=1: N==3*CDIM. Output tile staged in LDS (32 KB, swizzled) then
//            stored COALESCED (16B/lane): q (pre-scaled)/k -> [B,H,T,64],
//            v -> transposed-staged -> [B,H,64,T]. Fixes the r9-measured
//            16x/8x write amplification (WRITE_SIZE 641 MB vs 50 MB ideal).
// ---------------------------------------------------------------------------
template<int SCATTER>
__global__ __launch_bounds__(256)
void gemm_mfma(const ushort* __restrict__ A, const ushort* __restrict__ Bt,
               float* __restrict__ C0, ushort* __restrict__ Q0,
               ushort* __restrict__ K0, ushort* __restrict__ V0,
               int M, int N, int K)
{
    __shared__ __align__(16) char LDSb[32768];
    char* Asm = LDSb;            // 16 KB A-tile during K-loop
    char* Bsm = LDSb + 16384;    // 16 KB B-tile during K-loop

    const int tid  = threadIdx.x;
    const int wave = tid >> 6;
    const int lane = tid & 63;
    const int lr   = lane & 15;
    const int lg   = lane >> 4;
    const int wr   = wave >> 1;
    const int wc   = wave & 1;
    const int m0   = blockIdx.x * 128;
    const int n0   = blockIdx.y * 128;

    const int sr  = tid >> 1;
    const int sh  = (tid & 1) * 64;
    const int ssw = (sr & 7) << 4;

    const f32x4 zero4 = {0.f, 0.f, 0.f, 0.f};
    f32x4 acc[4][4];
    #pragma unroll
    for (int i = 0; i < 4; ++i)
        #pragma unroll
        for (int j = 0; j < 4; ++j) acc[i][j] = zero4;

    const char* Ag = (const char*)(A + (size_t)(m0 + sr) * K) + sh;
    const char* Bg = (const char*)(Bt + (size_t)(n0 + sr) * K) + sh;

    for (int k0 = 0; k0 < K; k0 += 64) {
        int4 av[4], bv[4];
        #pragma unroll
        for (int i = 0; i < 4; ++i) {
            av[i] = *(const int4*)(Ag + (size_t)k0 * 2 + i * 16);
            bv[i] = *(const int4*)(Bg + (size_t)k0 * 2 + i * 16);
        }
        __syncthreads();
        #pragma unroll
        for (int i = 0; i < 4; ++i) {
            *(int4*)(Asm + sr * 128 + ((sh + i * 16) ^ ssw)) = av[i];
            *(int4*)(Bsm + sr * 128 + ((sh + i * 16) ^ ssw)) = bv[i];
        }
        __syncthreads();

        #pragma unroll
        for (int ks = 0; ks < 2; ++ks) {
            bf16x8 af[4], bf[4];
            #pragma unroll
            for (int mt = 0; mt < 4; ++mt) {
                const int row = wr * 64 + mt * 16 + lr;
                af[mt] = *(const bf16x8*)(Asm + row * 128 +
                         ((ks * 64 + lg * 16) ^ ((row & 7) << 4)));
            }
            #pragma unroll
            for (int nt = 0; nt < 4; ++nt) {
                const int row = wc * 64 + nt * 16 + lr;
                bf[nt] = *(const bf16x8*)(Bsm + row * 128 +
                         ((ks * 64 + lg * 16) ^ ((row & 7) << 4)));
            }
            #pragma unroll
            for (int mt = 0; mt < 4; ++mt)
                #pragma unroll
                for (int nt = 0; nt < 4; ++nt)
                    acc[mt][nt] = __builtin_amdgcn_mfma_f32_16x16x32_bf16(
                        af[mt], bf[nt], acc[mt][nt], 0, 0, 0);
        }
    }

    if (SCATTER == 0) {
        #pragma unroll
        for (int mt = 0; mt < 4; ++mt)
            #pragma unroll
            for (int r4 = 0; r4 < 4; ++r4) {
                const int m = m0 + wr * 64 + mt * 16 + lg * 4 + r4;
                float* cr = C0 + (size_t)m * N + n0 + wc * 64;
                #pragma unroll
                for (int nt = 0; nt < 4; ++nt)
                    cr[nt * 16 + lr] = acc[mt][nt][r4];
            }
    } else {
        const int which = n0 >> 10;            // 0=q 1=k 2=v
        const int nn  = n0 & (CDIM - 1);
        const int h0  = nn >> 6;               // tile covers heads h0, h0+1
        const int b   = m0 >> 11;
        const int t0t = m0 & (T_SEQ - 1);
        __syncthreads();                       // frag reads done; reuse LDS
        if (which < 2) {
            const float qs = (which == 0) ? QSCALE : 1.0f;
            // stage [t_local][col] bf16, XOR-swizzled rows of 256B
            #pragma unroll
            for (int mt = 0; mt < 4; ++mt)
                #pragma unroll
                for (int r4 = 0; r4 < 4; ++r4) {
                    const int row = wr * 64 + mt * 16 + lg * 4 + r4;
                    char* rp = LDSb + row * 256;
                    const int swr = (row & 7) << 4;
                    #pragma unroll
                    for (int nt = 0; nt < 4; ++nt) {
                        const int col = wc * 64 + nt * 16 + lr;
                        *(ushort*)(rp + ((col * 2) ^ swr)) =
                            f2bf(acc[mt][nt][r4] * qs);
                    }
                }
            __syncthreads();
            // coalesced store: 2048 x 16B chunks, row-major over the tile
            ushort* dstb = ((which == 0) ? Q0 : K0) + (size_t)(b * NH) * T_SEQ * HD;
            #pragma unroll
            for (int it = 0; it < 8; ++it) {
                const int cid  = it * 256 + tid;
                const int row  = cid >> 4;            // t_local
                const int colb = (cid & 15) * 16;     // byte col in 256B row
                int4 vdat = *(const int4*)(LDSb + row * 256 +
                                           (colb ^ ((row & 7) << 4)));
                const int col = colb >> 1;            // element col 0..127
                const int h   = h0 + (col >> 6);
                const int dc  = col & 63;
                *(int4*)&dstb[((size_t)h * T_SEQ + t0t + row) * HD + dc] = vdat;
            }
        } else {
            // stage TRANSPOSED: [col][t_local] bf16 so vT stores are coalesced
            #pragma unroll
            for (int mt = 0; mt < 4; ++mt)
                #pragma unroll
                for (int r4 = 0; r4 < 4; ++r4) {
                    const int trow = wr * 64 + mt * 16 + lg * 4 + r4;  // t_local
                    #pragma unroll
                    for (int nt = 0; nt < 4; ++nt) {
                        const int col = wc * 64 + nt * 16 + lr;
                        *(ushort*)(LDSb + col * 256 +
                                   ((trow * 2) ^ ((col & 7) << 4))) =
                            f2bf(acc[mt][nt][r4]);
                    }
                }
            __syncthreads();
            ushort* vbase = V0 + (size_t)(b * NH) * HD * T_SEQ;
            #pragma unroll
            for (int it = 0; it < 8; ++it) {
                const int cid = it * 256 + tid;
                const int col = cid >> 4;             // h*64+d
                const int tb  = (cid & 15) * 16;      // byte offset in t-row
                int4 vdat = *(const int4*)(LDSb + col * 256 +
                                           (tb ^ ((col & 7) << 4)));
                const int h = h0 + (col >> 6);
                const int d = col & 63;
                *(int4*)&vbase[((size_t)h * HD + d) * T_SEQ + t0t + (tb >> 1)] = vdat;
            }
        }
    }
}

// ---------------------------------------------------------------------------
// Flash attention, bf16 MFMA, causal + rel-bias. 512 threads = 8 waves, each
// wave owns 16 q-rows (QBLK=128). exp2-domain softmax (q pre-scaled, bias
// pre-scaled by log2e). Async-stage split: next tile's global loads issued
// before compute, LDS write after barrier. 2 barriers per k-tile (P buffer is
// wave-private). Big q-tiles dispatched first. (verified r9: 598->452 total)
// ---------------------------------------------------------------------------
__global__ __launch_bounds__(512, 4)
void attn_mfma(const ushort* __restrict__ qb, const ushort* __restrict__ kb,
               const ushort* __restrict__ vb, const float* __restrict__ rb,
               ushort* __restrict__ y)
{
    __shared__ __align__(16) char KsB[64 * 128];      // 8 KB
    __shared__ __align__(16) char VtB[64 * 128];      // 8 KB
    __shared__ __align__(16) char PsB[8][16 * 128];   // 16 KB
    __shared__ float rbs[T_SEQ];                      // 8 KB (scaled by log2e)

    const int tid  = threadIdx.x;
    const int wave = tid >> 6;
    const int lane = tid & 63;
    const int lr   = lane & 15;
    const int lg   = lane >> 4;
    const int bh   = blockIdx.x;          // bh fastest; big q-tiles first in y
    const int h    = bh & (NH - 1);
    const int b    = bh >> 4;
    const int qt   = (int)gridDim.y - 1 - (int)blockIdx.y;
    const int q0   = qt * 128;

    for (int i = tid; i < q0 + 128; i += 512)
        rbs[i] = rb[(size_t)i * NH + h] * LOG2E;

    const ushort* qrow = qb + ((size_t)bh * T_SEQ + q0 + wave * 16 + lr) * HD;
    const bf16x8 aq0 = *(const bf16x8*)(qrow + lg * 8);
    const bf16x8 aq1 = *(const bf16x8*)(qrow + 32 + lg * 8);

    const f32x4 zero4 = {0.f, 0.f, 0.f, 0.f};
    f32x4 Oa[4] = {zero4, zero4, zero4, zero4};
    float m_r[4], l_r[4];
    #pragma unroll
    for (int r4 = 0; r4 < 4; ++r4) { m_r[r4] = -3e38f; l_r[r4] = 0.f; }

    const char* kbp = (const char*)(kb + (size_t)bh * T_SEQ * HD);
    const char* vbp = (const char*)(vb + (size_t)bh * HD * T_SEQ);

    // staging: 512 threads x 16 B cover one 64x128B tile exactly
    const int r_st  = tid >> 3;
    const int cb    = (tid & 7) * 16;
    const int sw_st = (r_st & 7) << 4;

    const int nkt = 2 * (qt + 1);

    int4 kreg = *(const int4*)(kbp + (size_t)r_st * HD * 2 + cb);
    int4 vreg = *(const int4*)(vbp + (size_t)r_st * T_SEQ * 2 + cb);

    for (int kt = 0; kt < nkt; ++kt) {
        const int j0 = kt * 64;
        __syncthreads();                  // all waves done reading prev tile
        *(int4*)(KsB + r_st * 128 + (cb ^ sw_st)) = kreg;
        *(int4*)(VtB + r_st * 128 + (cb ^ sw_st)) = vreg;
        __syncthreads();                  // tile ready
        if (kt + 1 < nkt) {               // prefetch next tile (hides HBM lat)
            const int j1 = j0 + 64;
            kreg = *(const int4*)(kbp + (size_t)(j1 + r_st) * HD * 2 + cb);
            vreg = *(const int4*)(vbp + ((size_t)r_st * T_SEQ + j1) * 2 + cb);
        }

        // S = Q K^T (q pre-scaled: S already in exp2 domain after bias add)
        f32x4 sa[4] = {zero4, zero4, zero4, zero4};
        #pragma unroll
        for (int nt = 0; nt < 4; ++nt) {
            const int row = nt * 16 + lr;
            const int sw  = (row & 7) << 4;
            bf16x8 bk0 = *(const bf16x8*)(KsB + row * 128 + ((lg * 16) ^ sw));
            bf16x8 bk1 = *(const bf16x8*)(KsB + row * 128 + ((64 + lg * 16) ^ sw));
            sa[nt] = __builtin_amdgcn_mfma_f32_16x16x32_bf16(aq0, bk0, sa[nt], 0, 0, 0);
            sa[nt] = __builtin_amdgcn_mfma_f32_16x16x32_bf16(aq1, bk1, sa[nt], 0, 0, 0);
        }

        // online softmax, exp2 domain
        #pragma unroll
        for (int r4 = 0; r4 < 4; ++r4) {
            const int gi = q0 + wave * 16 + lg * 4 + r4;
            float sv[4];
            float smax = -3e38f;
            #pragma unroll
            for (int nt = 0; nt < 4; ++nt) {
                const int gj = j0 + nt * 16 + lr;
                float s = (gj <= gi) ? sa[nt][r4] + rbs[gi - gj] : -3e38f;
                sv[nt] = s;
                smax = fmaxf(smax, s);
            }
            smax = fmaxf(smax, __shfl_xor(smax, 1));
            smax = fmaxf(smax, __shfl_xor(smax, 2));
            smax = fmaxf(smax, __shfl_xor(smax, 4));
            smax = fmaxf(smax, __shfl_xor(smax, 8));
            const float mnew  = fmaxf(m_r[r4], smax);
            const float alpha = exp2f(m_r[r4] - mnew);
            float ps = 0.f;
            #pragma unroll
            for (int nt = 0; nt < 4; ++nt) {
                const float p = exp2f(sv[nt] - mnew);
                sv[nt] = p;
                ps += p;
            }
            ps += __shfl_xor(ps, 1);
            ps += __shfl_xor(ps, 2);
            ps += __shfl_xor(ps, 4);
            ps += __shfl_xor(ps, 8);
            l_r[r4] = l_r[r4] * alpha + ps;
            m_r[r4] = mnew;
            #pragma unroll
            for (int dt = 0; dt < 4; ++dt) Oa[dt][r4] *= alpha;

            const int prow = lg * 4 + r4;
            char* pw = PsB[wave] + prow * 128;
            const int swp = (prow & 7) << 4;
            #pragma unroll
            for (int nt = 0; nt < 4; ++nt)
                *(ushort*)(pw + (((nt * 16 + lr) * 2) ^ swp)) = f2bf(sv[nt]);
        }
        // no barrier: PsB is wave-private (lgkmcnt orders), VtB stable

        bf16x8 ap0 = *(const bf16x8*)(PsB[wave] + lr * 128 + ((lg * 16) ^ ((lr & 7) << 4)));
        bf16x8 ap1 = *(const bf16x8*)(PsB[wave] + lr * 128 + ((64 + lg * 16) ^ ((lr & 7) << 4)));
        #pragma unroll
        for (int dt = 0; dt < 4; ++dt) {
            const int row = dt * 16 + lr;
            const int sw  = (row & 7) << 4;
            bf16x8 bv0 = *(const bf16x8*)(VtB + row * 128 + ((lg * 16) ^ sw));
            bf16x8 bv1 = *(const bf16x8*)(VtB + row * 128 + ((64 + lg * 16) ^ sw));
            Oa[dt] = __builtin_amdgcn_mfma_f32_16x16x32_bf16(ap0, bv0, Oa[dt], 0, 0, 0);
            Oa[dt] = __builtin_amdgcn_mfma_f32_16x16x32_bf16(ap1, bv1, Oa[dt], 0, 0, 0);
        }
    }

    #pragma unroll
    for (int r4 = 0; r4 < 4; ++r4) {
        const int t = q0 + wave * 16 + lg * 4 + r4;
        const float inv = 1.0f / l_r[r4];
        ushort* yr = y + ((size_t)(b * T_SEQ + t)) * CDIM + h * HD;
        #pragma unroll
        for (int dt = 0; dt < 4; ++dt) yr[dt * 16 + lr] = f2bf(Oa[dt][r4] * inv);
    }
}

extern "C" void kernel_launch(void* const* d_in, const int* in_sizes, int n_in,
                              void* d_out, int out_size, void* d_ws, size_t ws_size,
                              hipStream_t stream)
{
    const float* x     = (const float*)d_in[0];   // [B,T,C]
    const float* Wqkv  = (const float*)d_in[1];   // [C,3C]
    const float* Wproj = (const float*)d_in[2];   // [C,C]
    const float* rb    = (const float*)d_in[3];   // [MAX_LEN,NH]
    float* out = (float*)d_out;                   // [B,T,C] fp32

    const size_t per = (size_t)BATCH * NH * T_SEQ * HD;   // 8.39M elems
    ushort* xb  = (ushort*)d_ws;                          // bf16 [M][C]
    ushort* wqT = xb + per;                               // bf16 [3C][C]
    ushort* wpT = wqT + (size_t)3 * CDIM * CDIM;          // bf16 [C][C]
    ushort* qw  = wpT + (size_t)CDIM * CDIM;              // bf16 [B,H,T,64] (pre-scaled)
    ushort* kw  = qw + per;
    ushort* vw  = kw + per;                               // bf16 [B,H,64,T]
    ushort* yb  = vw + per;                               // bf16 [B,T,C]
    const size_t need = (per * 5 + (size_t)4 * CDIM * CDIM) * sizeof(ushort);
    if (ws_size < need) return;

    cvt_bf16<<<2048, 256, 0, stream>>>(x, xb, (int)(per / 4));
    transpose_cvt<<<dim3(3 * CDIM / 32, CDIM / 32), 256, 0, stream>>>(Wqkv, wqT, CDIM, 3 * CDIM);
    transpose_cvt<<<dim3(CDIM / 32, CDIM / 32), 256, 0, stream>>>(Wproj, wpT, CDIM, CDIM);

    dim3 g1(MROWS / 128, (3 * CDIM) / 128);               // 64 x 24
    gemm_mfma<1><<<g1, dim3(256), 0, stream>>>(xb, wqT, nullptr, qw, kw, vw,
                                               MROWS, 3 * CDIM, CDIM);

    dim3 g2(BATCH * NH, T_SEQ / 128);                     // 64 x 16, big-first in y
    attn_mfma<<<g2, dim3(512), 0, stream>>>(qw, kw, vw, rb, yb);

    dim3 g3(MROWS / 128, CDIM / 128);                     // 64 x 8
    gemm_mfma<0><<<g3, dim3(256), 0, stream>>>(yb, wpT, out, nullptr, nullptr, nullptr,
                                               MROWS, CDIM, CDIM);
}